// Round 6
// baseline (198.709 us; speedup 1.0000x reference)
//
#include <hip/hip_runtime.h>
#include <stdint.h>
#include <stddef.h>

// T=2048, B=4, E=1024, H=16, HD=64, N-heads = B*H = 64.
// qkv reshape: f in [0,3072) -> head hq = f/192, s3 = (f/64)%3, d = f%64, n = b*16+hq.
// Layouts: Qb,Kb,Vb = [n][t][d] bf16 ; VTb = [n][d][t] bf16 (separate transpose kernel).

typedef __attribute__((ext_vector_type(8))) short bf16x8;
typedef __attribute__((ext_vector_type(4))) float f32x4;
typedef __attribute__((ext_vector_type(4))) unsigned int u32x4;

#define MFMA16(a, b, c) __builtin_amdgcn_mfma_f32_16x16x32_bf16((a), (b), (c), 0, 0, 0)

__device__ __forceinline__ unsigned short f2bf(float f) {
  unsigned u = __builtin_bit_cast(unsigned, f);
  u += 0x7fffu + ((u >> 16) & 1u);   // RNE
  return (unsigned short)(u >> 16);
}

__device__ __forceinline__ float fast_exp2(float x) {
#if __has_builtin(__builtin_amdgcn_exp2f)
  return __builtin_amdgcn_exp2f(x);
#else
  return exp2f(x);
#endif
}

__device__ __forceinline__ unsigned cvtpk(float lo, float hi) {
  unsigned r;
  asm volatile("v_cvt_pk_bf16_f32 %0, %1, %2" : "=v"(r) : "v"(lo), "v"(hi));
  return r;
}

// a' = {a.lo32, b.lo32}, b' = {a.hi32, b.hi32}
__device__ __forceinline__ void lane_swap32(unsigned &a, unsigned &b) {
#if __has_builtin(__builtin_amdgcn_permlane32_swap)
  auto r = __builtin_amdgcn_permlane32_swap(a, b, false, false);
  a = r[0]; b = r[1];
#else
  const bool hi = (threadIdx.x & 32) != 0;
  unsigned sa = (unsigned)__shfl_xor((int)a, 32, 64);
  unsigned sb = (unsigned)__shfl_xor((int)b, 32, 64);
  unsigned na = hi ? sb : a;
  unsigned nb = hi ? b : sa;
  a = na; b = nb;
#endif
}

// a' = {a.g0, b.g0, a.g2, b.g2}, b' = {a.g1, b.g1, a.g3, b.g3} (16-lane groups)
__device__ __forceinline__ void lane_swap16(unsigned &a, unsigned &b) {
#if __has_builtin(__builtin_amdgcn_permlane16_swap)
  auto r = __builtin_amdgcn_permlane16_swap(a, b, false, false);
  a = r[0]; b = r[1];
#else
  const bool odd = (threadIdx.x & 16) != 0;
  unsigned sa = (unsigned)__shfl_xor((int)a, 16, 64);
  unsigned sb = (unsigned)__shfl_xor((int)b, 16, 64);
  unsigned na = odd ? sb : a;
  unsigned nb = odd ? b : sa;
  a = na; b = nb;
#endif
}

__device__ __forceinline__ void gload_lds16(const void* g, void* l) {
  __builtin_amdgcn_global_load_lds((const __attribute__((address_space(1))) void*)g,
                                   (__attribute__((address_space(3))) void*)l,
                                   16, 0, 0);
}

// ---------------- fp32 -> bf16 convert ----------------
__global__ __launch_bounds__(256) void k_cvt(const float* __restrict__ src,
                                             unsigned short* __restrict__ dst, int n4) {
  int i = blockIdx.x * 256 + threadIdx.x;
  if (i >= n4) return;
  const float4 v = ((const float4*)src)[i];
  ushort4 o;
  o.x = f2bf(v.x); o.y = f2bf(v.y); o.z = f2bf(v.z); o.w = f2bf(v.w);
  ((ushort4*)dst)[i] = o;
}

// ---------------- GEMM1: X[8192][1024] x W1t[3072][1024] -> scatter Q/K/V ----------------
__global__ __launch_bounds__(256, 2) void k_gemm_qkv(
    const unsigned short* __restrict__ A,
    const unsigned short* __restrict__ Bt,
    unsigned short* __restrict__ Qb,        // [64][2048][64]
    unsigned short* __restrict__ Kb,        // [64][2048][64]
    unsigned short* __restrict__ Vb) {      // [64][2048][64]
  constexpr int K = 1024;
  __shared__ __align__(16) unsigned short As[128 * 32];
  __shared__ __align__(16) unsigned short Bs[128 * 32];
  const int tid = threadIdx.x;
  const int l = tid & 63, w = tid >> 6;
  const int lr = l & 15, lg = l >> 4;
  const int bm = blockIdx.x, bn = blockIdx.y;
  const int wr = (w >> 1) * 64, wc = (w & 1) * 64;

  f32x4 acc[4][4] = {};

  const int o0 = tid * 16, o1 = tid * 16 + 4096;
  const int r0 = o0 >> 6, c0 = o0 & 63;
  const int r1 = o1 >> 6, c1 = o1 & 63;
  const char* gA0 = (const char*)A + (size_t)(bm * 128 + r0) * (K * 2) + c0;
  const char* gA1 = (const char*)A + (size_t)(bm * 128 + r1) * (K * 2) + c1;
  const char* gB0 = (const char*)Bt + (size_t)(bn * 128 + r0) * (K * 2) + c0;
  const char* gB1 = (const char*)Bt + (size_t)(bn * 128 + r1) * (K * 2) + c1;
  char* lA0 = (char*)As + o0;
  char* lA1 = (char*)As + o1;
  char* lB0 = (char*)Bs + o0;
  char* lB1 = (char*)Bs + o1;

  for (int kt = 0; kt < K / 32; ++kt) {
    const int kb = kt * 64;
    gload_lds16(gA0 + kb, lA0);
    gload_lds16(gA1 + kb, lA1);
    gload_lds16(gB0 + kb, lB0);
    gload_lds16(gB1 + kb, lB1);
    __syncthreads();
    bf16x8 af[4], bfr[4];
#pragma unroll
    for (int mf = 0; mf < 4; ++mf)
      af[mf] = *(const bf16x8*)&As[(wr + mf * 16 + lr) * 32 + lg * 8];
#pragma unroll
    for (int nf = 0; nf < 4; ++nf)
      bfr[nf] = *(const bf16x8*)&Bs[(wc + nf * 16 + lr) * 32 + lg * 8];
#pragma unroll
    for (int mf = 0; mf < 4; ++mf)
#pragma unroll
      for (int nf = 0; nf < 4; ++nf)
        acc[mf][nf] = MFMA16(af[mf], bfr[nf], acc[mf][nf]);
    __syncthreads();
  }

  // D layout: col = lane&15, row = (lane>>4)*4 + i. Coalesced [n][t][d] for Q,K,V.
#pragma unroll
  for (int nf = 0; nf < 4; ++nf) {
    const int f = bn * 128 + wc + nf * 16 + lr;
    const int hq = f / 192;
    const int s3 = (f >> 6) % 3;
    const int d = f & 63;
    unsigned short* dst = (s3 == 0) ? Qb : (s3 == 1) ? Kb : Vb;
    // fold SCALE*log2(e) into Q so softmax is a bare exp2
    const float qscale = (s3 == 0) ? 0.18033688011112042f : 1.0f;
#pragma unroll
    for (int mf = 0; mf < 4; ++mf) {
#pragma unroll
      for (int i = 0; i < 4; ++i) {
        const int r = bm * 128 + wr + mf * 16 + lg * 4 + i;
        const int t = r >> 2, bb2 = r & 3;
        const int nIdx = bb2 * 16 + hq;
        dst[((size_t)nIdx * 2048 + t) * 64 + d] = f2bf(acc[mf][nf][i] * qscale);
      }
    }
  }
}

// ---------------- V transpose: [n][t][d] -> [n][d][t] ----------------
__global__ __launch_bounds__(256) void k_vtrans(const unsigned short* __restrict__ V,
                                                unsigned short* __restrict__ VT) {
  __shared__ unsigned short tile[64][66];
  const int tid = threadIdx.x;
  const int n = blockIdx.y, t0 = blockIdx.x * 64;
  const int r = tid >> 2, c0 = (tid & 3) * 16;
  const unsigned short* src = V + ((size_t)(n * 2048 + t0 + r) * 64 + c0);
  bf16x8 a = *(const bf16x8*)src;
  bf16x8 b = *(const bf16x8*)(src + 8);
#pragma unroll
  for (int j = 0; j < 8; ++j) tile[r][c0 + j] = (unsigned short)a[j];
#pragma unroll
  for (int j = 0; j < 8; ++j) tile[r][c0 + 8 + j] = (unsigned short)b[j];
  __syncthreads();
  const int d = tid >> 2, u0 = (tid & 3) * 16;
  bf16x8 oA, oB;
#pragma unroll
  for (int j = 0; j < 8; ++j) oA[j] = (short)tile[u0 + j][d];
#pragma unroll
  for (int j = 0; j < 8; ++j) oB[j] = (short)tile[u0 + 8 + j][d];
  unsigned short* dst = VT + ((size_t)(n * 64 + d) * 2048 + t0 + u0);
  *(bf16x8*)dst = oA;
  *(bf16x8*)(dst + 8) = oB;
}

// ---------------- flash attention: q=256/block, 4-ring counted-vmcnt pipeline ----------------
__global__ __launch_bounds__(256, 2) void k_attn(
    const unsigned short* __restrict__ Qb, const unsigned short* __restrict__ Kb,
    const unsigned short* __restrict__ VTb, unsigned short* __restrict__ Cx) {
  __shared__ __align__(16) unsigned short Ks[4][64 * 64];  // [s][d], xor-swizzled, 4-ring
  __shared__ __align__(16) unsigned short Vt[4][64 * 64];  // [d][s], xor-swizzled, 4-ring

  const int tid = threadIdx.x;
  const int l = tid & 63, w = tid >> 6;
  const int lq = l & 15, lg = l >> 4;
  const int n = blockIdx.x, qt = blockIdx.y;   // x = head -> all q-tiles of a head on one XCD

  const unsigned short* Qh = Qb + (size_t)n * (2048 * 64);
  const unsigned short* Kh = Kb + (size_t)n * (2048 * 64);
  const unsigned short* Vh = VTb + (size_t)n * (64 * 2048);

  // Q fragments (B-operand of swapped QK^T): q = qt*256 + w*64 + qf*16 + lq
  bf16x8 aq[4][2];
#pragma unroll
  for (int qf = 0; qf < 4; ++qf)
#pragma unroll
    for (int kd = 0; kd < 2; ++kd)
      aq[qf][kd] = *(const bf16x8*)&Qh[(size_t)(qt * 256 + w * 64 + qf * 16 + lq) * 64 +
                                       kd * 32 + lg * 8];

  f32x4 o[4][4] = {};       // O^T acc: [df][qf]; lane: q = lq, d = df*16 + lg*4 + i
  float lsum[4] = {0.f, 0.f, 0.f, 0.f};

  char* Ksl = (char*)&Ks[0][0];
  char* Vtl = (char*)&Vt[0][0];

  // 4 loads per thread per call (vmcnt += 4)
  auto STAGE = [&](int buf, int st) {
    const int s0 = st * 64;
#pragma unroll
    for (int it = 0; it < 2; ++it) {
      const int off = (it * 256 + tid) * 16;
      const int row = off >> 7;
      const int colb = (off & 127) ^ ((row & 7) << 4);
      gload_lds16((const char*)Kh + ((size_t)(s0 + row) << 7) + colb, Ksl + buf * 8192 + off);
      gload_lds16((const char*)Vh + ((size_t)row << 12) + (s0 << 1) + colb, Vtl + buf * 8192 + off);
    }
  };

  // prologue: 2 tiles in flight; wait for tile 0 only (counted)
  STAGE(0, 0);
  STAGE(1, 1);
  asm volatile("s_waitcnt vmcnt(4)" ::: "memory");
  __builtin_amdgcn_s_barrier();

#pragma unroll 4
  for (int st = 0; st < 32; ++st) {
    const int cur = st & 3;
    // stage tile st+2 (tail: harmless dummy re-stage of 31 keeps vmcnt arithmetic uniform)
    STAGE((st + 2) & 3, (st + 2 < 32) ? st + 2 : 31);

    const char* Kc = Ksl + cur * 8192;
    const char* Vc = Vtl + cur * 8192;

    __builtin_amdgcn_s_setprio(1);
#pragma unroll
    for (int kb = 0; kb < 2; ++kb) {
      // K fragments for s-block [kb*32, kb*32+32): rows (2kb+sfl)*16 + lq
      bf16x8 kf[2][2];
#pragma unroll
      for (int sfl = 0; sfl < 2; ++sfl) {
        const int rowk = (2 * kb + sfl) * 16 + lq;
        const int sw = (rowk & 7) << 4;
        kf[sfl][0] = *(const bf16x8*)(Kc + ((rowk * 128 + lg * 16) ^ sw));
        kf[sfl][1] = *(const bf16x8*)(Kc + ((rowk * 128 + 64 + lg * 16) ^ sw));
      }

      // QK^T + softmax + in-register P->B-frag exchange, per qf
      bf16x8 pq[4];
#pragma unroll
      for (int qf = 0; qf < 4; ++qf) {
        f32x4 s0 = {0.f, 0.f, 0.f, 0.f};
        f32x4 s1 = {0.f, 0.f, 0.f, 0.f};
        s0 = MFMA16(kf[0][0], aq[qf][0], s0);
        s0 = MFMA16(kf[0][1], aq[qf][1], s0);
        s1 = MFMA16(kf[1][0], aq[qf][0], s1);
        s1 = MFMA16(kf[1][1], aq[qf][1], s1);
        float accs = 0.f;
#pragma unroll
        for (int i = 0; i < 4; ++i) {
          s0[i] = fast_exp2(s0[i]);
          s1[i] = fast_exp2(s1[i]);
          accs += s0[i] + s1[i];
        }
        lsum[qf] += accs;
        unsigned w0 = cvtpk(s0[0], s0[1]);
        unsigned w1 = cvtpk(s0[2], s0[3]);
        unsigned w2 = cvtpk(s1[0], s1[1]);
        unsigned w3 = cvtpk(s1[2], s1[3]);
        lane_swap32(w0, w2);
        lane_swap32(w1, w3);
        lane_swap16(w0, w2);
        lane_swap16(w1, w3);
        u32x4 t4 = {w0, w1, w2, w3};
        pq[qf] = __builtin_bit_cast(bf16x8, t4);
      }

      // PV for this s-block: O^T += V^T(:, kb) . P^T
#pragma unroll
      for (int df = 0; df < 4; ++df) {
        const int rowd = df * 16 + lq;
        const int sw = (rowd & 7) << 4;
        bf16x8 vf = *(const bf16x8*)(Vc + ((rowd * 128 + kb * 64 + lg * 16) ^ sw));
#pragma unroll
        for (int qf = 0; qf < 4; ++qf)
          o[df][qf] = MFMA16(vf, pq[qf], o[df][qf]);
      }
    }
    __builtin_amdgcn_s_setprio(0);

    // counted wait: only tile st+1's 4 loads must be done (st+2's 4 may stay in flight)
    asm volatile("s_waitcnt vmcnt(4)" ::: "memory");
    __builtin_amdgcn_s_barrier();
    __builtin_amdgcn_sched_barrier(0);
  }

  // epilogue: reduce lsum over lane-groups, normalize, store
  const int bb = n >> 4, h = n & 15;
#pragma unroll
  for (int qf = 0; qf < 4; ++qf) {
    float li = lsum[qf];
    li += __shfl_xor(li, 16, 64);
    li += __shfl_xor(li, 32, 64);
    const float inv = 1.0f / li;
    const int q = qt * 256 + w * 64 + qf * 16 + lq;
#pragma unroll
    for (int df = 0; df < 4; ++df) {
      ushort4 pk;
      pk.x = f2bf(o[df][qf][0] * inv);
      pk.y = f2bf(o[df][qf][1] * inv);
      pk.z = f2bf(o[df][qf][2] * inv);
      pk.w = f2bf(o[df][qf][3] * inv);
      *(ushort4*)&Cx[(size_t)(q * 4 + bb) * 1024 + h * 64 + df * 16 + lg * 4] = pk;
    }
  }
}

// ---------------- GEMM4: ctx[8192][1024] x Wot[1024][1024] -> out fp32 ----------------
__global__ __launch_bounds__(256, 2) void k_gemm_out(
    const unsigned short* __restrict__ A,
    const unsigned short* __restrict__ Bt,
    float* __restrict__ C) {
  constexpr int K = 1024;
  __shared__ __align__(16) unsigned short As[128 * 32];
  __shared__ __align__(16) unsigned short Bs[128 * 32];
  const int tid = threadIdx.x;
  const int l = tid & 63, w = tid >> 6;
  const int lr = l & 15, lg = l >> 4;
  const int bm = blockIdx.x, bn = blockIdx.y;
  const int wr = (w >> 1) * 64, wc = (w & 1) * 64;

  f32x4 acc[4][4] = {};

  const int o0 = tid * 16, o1 = tid * 16 + 4096;
  const int r0 = o0 >> 6, c0 = o0 & 63;
  const int r1 = o1 >> 6, c1 = o1 & 63;
  const char* gA0 = (const char*)A + (size_t)(bm * 128 + r0) * (K * 2) + c0;
  const char* gA1 = (const char*)A + (size_t)(bm * 128 + r1) * (K * 2) + c1;
  const char* gB0 = (const char*)Bt + (size_t)(bn * 128 + r0) * (K * 2) + c0;
  const char* gB1 = (const char*)Bt + (size_t)(bn * 128 + r1) * (K * 2) + c1;
  char* lA0 = (char*)As + o0;
  char* lA1 = (char*)As + o1;
  char* lB0 = (char*)Bs + o0;
  char* lB1 = (char*)Bs + o1;

  for (int kt = 0; kt < K / 32; ++kt) {
    const int kb = kt * 64;
    gload_lds16(gA0 + kb, lA0);
    gload_lds16(gA1 + kb, lA1);
    gload_lds16(gB0 + kb, lB0);
    gload_lds16(gB1 + kb, lB1);
    __syncthreads();
    bf16x8 af[4], bfr[4];
#pragma unroll
    for (int mf = 0; mf < 4; ++mf)
      af[mf] = *(const bf16x8*)&As[(wr + mf * 16 + lr) * 32 + lg * 8];
#pragma unroll
    for (int nf = 0; nf < 4; ++nf)
      bfr[nf] = *(const bf16x8*)&Bs[(wc + nf * 16 + lr) * 32 + lg * 8];
#pragma unroll
    for (int mf = 0; mf < 4; ++mf)
#pragma unroll
      for (int nf = 0; nf < 4; ++nf)
        acc[mf][nf] = MFMA16(af[mf], bfr[nf], acc[mf][nf]);
    __syncthreads();
  }

#pragma unroll
  for (int mf = 0; mf < 4; ++mf)
#pragma unroll
    for (int i = 0; i < 4; ++i) {
      const int r = bm * 128 + wr + mf * 16 + lg * 4 + i;
#pragma unroll
      for (int nf = 0; nf < 4; ++nf)
        C[(size_t)r * 1024 + bn * 128 + wc + nf * 16 + lr] = acc[mf][nf][i];
    }
}

// ---------------- host launch ----------------
extern "C" void kernel_launch(void* const* d_in, const int* in_sizes, int n_in,
                              void* d_out, int out_size, void* d_ws, size_t ws_size,
                              hipStream_t stream) {
  const float* X = (const float*)d_in[0];    // (2048,4,1024)
  const float* W1 = (const float*)d_in[1];   // (3072,1024)
  const float* Wo = (const float*)d_in[2];   // (1024,1024)
  float* out = (float*)d_out;                // (2048,4,1024) fp32

  char* ws = (char*)d_ws;
  unsigned short* Xb  = (unsigned short*)(ws);              // 16 MB
  unsigned short* W1b = (unsigned short*)(ws + 16777216);   //  6 MB
  unsigned short* Wob = (unsigned short*)(ws + 23068672);   //  2 MB
  unsigned short* Qb  = (unsigned short*)(ws + 25165824);   // 16 MB
  unsigned short* Kb  = (unsigned short*)(ws + 41943040);   // 16 MB
  unsigned short* VTb = (unsigned short*)(ws + 58720256);   // 16 MB
  // Vb aliases the Cx slot: Vb is dead after k_vtrans, Cx written only by k_attn (later).
  unsigned short* Vb  = (unsigned short*)(ws + 75497472);   // 16 MB
  unsigned short* Cx  = (unsigned short*)(ws + 75497472);   // same 16 MB

  k_cvt<<<8192, 256, 0, stream>>>(X, Xb, 2097152);
  k_cvt<<<3072, 256, 0, stream>>>(W1, W1b, 786432);
  k_cvt<<<1024, 256, 0, stream>>>(Wo, Wob, 262144);
  k_gemm_qkv<<<dim3(64, 24), 256, 0, stream>>>(Xb, W1b, Qb, Kb, Vb);
  k_vtrans<<<dim3(32, 64), 256, 0, stream>>>(Vb, VTb);
  k_attn<<<dim3(64, 8), 256, 0, stream>>>(Qb, Kb, VTb, Cx);
  k_gemm_out<<<dim3(64, 8), 256, 0, stream>>>(Cx, Wob, out);
}